// Round 1
// baseline (394.258 us; speedup 1.0000x reference)
//
#include <hip/hip_runtime.h>
#include <hip/hip_bf16.h>
#include <stdint.h>

typedef __attribute__((ext_vector_type(8))) short short8;
typedef __attribute__((ext_vector_type(4))) float f32x4;
typedef __hip_bfloat16 bf16;

typedef __attribute__((address_space(3))) uint32_t lds_u32_t;
typedef __attribute__((address_space(1))) const uint32_t glb_u32_t;

__device__ __forceinline__ void gload_lds16(const void* g, void* l) {
  // stages 64 lanes x 16B: LDS dest = l + lane*16 (wave-uniform base), global src per-lane
  __builtin_amdgcn_global_load_lds((glb_u32_t*)g, (lds_u32_t*)l, 16, 0, 0);
}

// ---------------- prep kernels ----------------

__global__ void conv_bf16(const float* __restrict__ in, bf16* __restrict__ outp, int n4) {
  int i = blockIdx.x * blockDim.x + threadIdx.x;
  if (i >= n4) return;
  const float4 v = ((const float4*)in)[i];
  union { ushort4 u; bf16 h[4]; } o;
  o.h[0] = __float2bfloat16(v.x); o.h[1] = __float2bfloat16(v.y);
  o.h[2] = __float2bfloat16(v.z); o.h[3] = __float2bfloat16(v.w);
  ((ushort4*)outp)[i] = o.u;
}

// W [1024][1024] f32 row-major -> WT [n][k] bf16  (4 matrices via blockIdx.z)
__global__ void transpose_w(const float* __restrict__ W0, const float* __restrict__ W1,
                            const float* __restrict__ W2, const float* __restrict__ W3,
                            bf16* __restrict__ outp) {
  const float* W = blockIdx.z == 0 ? W0 : blockIdx.z == 1 ? W1 : blockIdx.z == 2 ? W2 : W3;
  bf16* o = outp + (size_t)blockIdx.z * 1048576;
  __shared__ float t[32][33];
  int x = threadIdx.x, y0 = threadIdx.y;            // (32,8)
  int c0 = blockIdx.x * 32, r0 = blockIdx.y * 32;
#pragma unroll
  for (int i = 0; i < 4; i++)
    t[y0 + i*8][x] = W[(size_t)(r0 + y0 + i*8)*1024 + c0 + x];
  __syncthreads();
#pragma unroll
  for (int i = 0; i < 4; i++)
    o[(size_t)(c0 + y0 + i*8)*1024 + r0 + x] = __float2bfloat16(t[x][y0 + i*8]);
}

// attention_mask [B,1,S,S] int32 -> bit-packed words: bit=1 means masked (mask==0)
__global__ void maskpack(const int* __restrict__ mask, unsigned long long* __restrict__ mbits) {
  int tid = threadIdx.x;
  int lane = tid & 63, wid = tid >> 6;
  size_t word = (size_t)blockIdx.x * 4 + wid;       // 262144 words total
  int v = mask[word * 64 + lane];
  unsigned long long bits = __ballot(v == 0);
  if (lane == 0) mbits[word] = bits;
}

// ---------------- GEMM (B-transposed): C[M=8192][N=1024] = A[M][1024] * Bt[N][1024]^T ----------------
// MODE 0: write bf16 to [B,H,S,64]  (Q,K)
// MODE 1: write bf16 to [B,H,64,S]  (V pre-transposed)
// MODE 2: write f32 row-major + bias (final output)
template<int MODE>
__global__ void gemm_bt(const bf16* __restrict__ A, const bf16* __restrict__ Bt,
                        void* __restrict__ Out, const float* __restrict__ bias) {
  const int tid = threadIdx.x;
  const int lane = tid & 63, wid = tid >> 6;
  const int g = lane >> 4, c = lane & 15;
  const int m0 = blockIdx.x * 128, n0 = blockIdx.y * 128;
  const int wm = wid >> 1, wn = wid & 1;
  __shared__ bf16 As[128 * 64];
  __shared__ bf16 Bs[128 * 64];
  f32x4 acc[4][4] = {};
  for (int k0 = 0; k0 < 1024; k0 += 64) {
#pragma unroll
    for (int i = 0; i < 4; i++) {
      int chunk = wid * 4 + i;          // 16 chunks of 1KB per matrix
      int idx = chunk * 64 + lane;      // 16B unit index
      int row = idx >> 3, u = idx & 7;  // 128B rows, 8 units each
      int koff = k0 + ((u ^ (row & 7)) * 8);   // pre-swizzled source (rule #21)
      gload_lds16(A  + (size_t)(m0 + row) * 1024 + koff, As + chunk * 512);
      gload_lds16(Bt + (size_t)(n0 + row) * 1024 + koff, Bs + chunk * 512);
    }
    __syncthreads();
#pragma unroll
    for (int kk = 0; kk < 2; kk++) {
      short8 af[4], bf_[4];
#pragma unroll
      for (int f = 0; f < 4; f++) {
        int ra = wm * 64 + f * 16 + c;
        af[f]  = *(const short8*)(As + ra * 64 + (((kk * 4 + g) ^ (ra & 7)) * 8));
        int rb = wn * 64 + f * 16 + c;
        bf_[f] = *(const short8*)(Bs + rb * 64 + (((kk * 4 + g) ^ (rb & 7)) * 8));
      }
#pragma unroll
      for (int fm = 0; fm < 4; fm++)
#pragma unroll
        for (int fn = 0; fn < 4; fn++)
          acc[fm][fn] = __builtin_amdgcn_mfma_f32_16x16x32_bf16(af[fm], bf_[fn], acc[fm][fn], 0, 0, 0);
    }
    __syncthreads();
  }
  // epilogue: C layout col = lane&15, row = (lane>>4)*4 + reg
#pragma unroll
  for (int fm = 0; fm < 4; fm++) {
#pragma unroll
    for (int fn = 0; fn < 4; fn++) {
      int gn = n0 + wn * 64 + fn * 16 + c;
#pragma unroll
      for (int r = 0; r < 4; r++) {
        int gm = m0 + wm * 64 + fm * 16 + g * 4 + r;
        float v = acc[fm][fn][r];
        if constexpr (MODE == 2) {
          ((float*)Out)[(size_t)gm * 1024 + gn] = v + bias[gn];
        } else if constexpr (MODE == 0) {
          int b = gm >> 11, s = gm & 2047, hh = gn >> 6, d = gn & 63;
          ((bf16*)Out)[(((size_t)b * 16 + hh) * 2048 + s) * 64 + d] = __float2bfloat16(v);
        } else {
          int b = gm >> 11, s = gm & 2047, hh = gn >> 6, d = gn & 63;
          ((bf16*)Out)[(((size_t)b * 16 + hh) * 64 + d) * 2048 + s] = __float2bfloat16(v);
        }
      }
    }
  }
}

// ---------------- flash attention ----------------
// grid (S/128=16, B*H=64), 256 threads. Wave w owns 32 q rows. KT=64.
__global__ __launch_bounds__(256, 2) void attn_kernel(
    const bf16* __restrict__ Qb, const bf16* __restrict__ Kb, const bf16* __restrict__ Vt,
    const unsigned long long* __restrict__ mbits, bf16* __restrict__ ctx) {
  const int tid = threadIdx.x;
  const int lane = tid & 63, wid = tid >> 6;
  const int g = lane >> 4, c = lane & 15;
  const int bh = blockIdx.y;
  const int b = bh >> 4, h = bh & 15;
  const int qb0 = blockIdx.x * 128 + wid * 32;
  __shared__ bf16 Ks[64 * 64];
  __shared__ bf16 Vs[64 * 64];          // V^T tile: [dh][key]
  __shared__ bf16 Ps[4][32 * 72];       // per-wave P tile, padded stride 72
  const bf16* Qp = Qb + (size_t)bh * 2048 * 64;
  const bf16* Kp = Kb + (size_t)bh * 2048 * 64;
  const bf16* Vp = Vt + (size_t)bh * 64 * 2048;

  short8 qf[2][2];
#pragma unroll
  for (int fm = 0; fm < 2; fm++)
#pragma unroll
    for (int kk = 0; kk < 2; kk++)
      qf[fm][kk] = *(const short8*)(Qp + (size_t)(qb0 + fm * 16 + c) * 64 + kk * 32 + g * 8);

  f32x4 Oacc[2][4] = {};
  float mrun[2][4], lrun[2][4];
#pragma unroll
  for (int fm = 0; fm < 2; fm++)
#pragma unroll
    for (int r = 0; r < 4; r++) { mrun[fm][r] = -3.0e38f; lrun[fm][r] = 0.f; }

  const float C1 = 0.18033688011112042f;       // (1/8)*log2(e): logits in log2 units
  const float XMASK = -1.8033688011112042e8f;  // (-1e9) * C1  (mask BEFORE scale, as reference)

  for (int kt = 0; kt < 32; kt++) {
#pragma unroll
    for (int i = 0; i < 2; i++) {
      int chunk = wid * 2 + i;
      int idx = chunk * 64 + lane;
      int row = idx >> 3, u = idx & 7;
      gload_lds16(Kp + (size_t)(kt * 64 + row) * 64 + ((u ^ (row & 7)) * 8), Ks + chunk * 512);
      gload_lds16(Vp + (size_t)row * 2048 + kt * 64 + ((u ^ (row & 7)) * 8), Vs + chunk * 512);
    }
    __syncthreads();
    // QK^T : scores[q][key]
    f32x4 sacc[2][4] = {};
#pragma unroll
    for (int kk = 0; kk < 2; kk++) {
      short8 bK[4];
#pragma unroll
      for (int fn = 0; fn < 4; fn++) {
        int row = fn * 16 + c;
        bK[fn] = *(const short8*)(Ks + row * 64 + (((kk * 4 + g) ^ (row & 7)) * 8));
      }
#pragma unroll
      for (int fm = 0; fm < 2; fm++)
#pragma unroll
        for (int fn = 0; fn < 4; fn++)
          sacc[fm][fn] = __builtin_amdgcn_mfma_f32_16x16x32_bf16(qf[fm][kk], bK[fn], sacc[fm][fn], 0, 0, 0);
    }
    // mask + convert to log2-units logits (in place)
#pragma unroll
    for (int fm = 0; fm < 2; fm++) {
      unsigned long long mw[4];
#pragma unroll
      for (int r = 0; r < 4; r++)
        mw[r] = mbits[((size_t)b * 2048 + qb0 + fm * 16 + g * 4 + r) * 32 + kt];
#pragma unroll
      for (int fn = 0; fn < 4; fn++)
#pragma unroll
        for (int r = 0; r < 4; r++) {
          float xv = sacc[fm][fn][r] * C1;
          if ((mw[r] >> (fn * 16 + c)) & 1ull) xv = XMASK;
          sacc[fm][fn][r] = xv;
        }
    }
    // online softmax
#pragma unroll
    for (int fm = 0; fm < 2; fm++) {
      float mx[4];
#pragma unroll
      for (int r = 0; r < 4; r++)
        mx[r] = fmaxf(fmaxf(sacc[fm][0][r], sacc[fm][1][r]), fmaxf(sacc[fm][2][r], sacc[fm][3][r]));
#pragma unroll
      for (int st = 1; st < 16; st <<= 1)
#pragma unroll
        for (int r = 0; r < 4; r++)
          mx[r] = fmaxf(mx[r], __shfl_xor(mx[r], st));
#pragma unroll
      for (int r = 0; r < 4; r++) {
        float mnew = fmaxf(mrun[fm][r], mx[r]);
        float sc = exp2f(mrun[fm][r] - mnew);
        mrun[fm][r] = mnew;
        lrun[fm][r] *= sc;
#pragma unroll
        for (int fn = 0; fn < 4; fn++) Oacc[fm][fn][r] *= sc;
      }
#pragma unroll
      for (int fn = 0; fn < 4; fn++)
#pragma unroll
        for (int r = 0; r < 4; r++) {
          float p = exp2f(sacc[fm][fn][r] - mrun[fm][r]);
          lrun[fm][r] += p;   // partial (this lane's columns only); full reduce at end
          Ps[wid][(fm * 16 + g * 4 + r) * 72 + fn * 16 + c] = __float2bfloat16(p);
        }
    }
    asm volatile("s_waitcnt lgkmcnt(0)" ::: "memory");  // P writes visible before reads
    __builtin_amdgcn_sched_barrier(0);
    // PV: O[q][dh] += P[q][key] * V[key][dh]
#pragma unroll
    for (int kk = 0; kk < 2; kk++) {
      short8 pa[2], bV[4];
#pragma unroll
      for (int fm = 0; fm < 2; fm++)
        pa[fm] = *(const short8*)(&Ps[wid][(fm * 16 + c) * 72 + kk * 32 + g * 8]);
#pragma unroll
      for (int fn = 0; fn < 4; fn++) {
        int row = fn * 16 + c;
        bV[fn] = *(const short8*)(Vs + row * 64 + (((kk * 4 + g) ^ (row & 7)) * 8));
      }
#pragma unroll
      for (int fm = 0; fm < 2; fm++)
#pragma unroll
        for (int fn = 0; fn < 4; fn++)
          Oacc[fm][fn] = __builtin_amdgcn_mfma_f32_16x16x32_bf16(pa[fm], bV[fn], Oacc[fm][fn], 0, 0, 0);
    }
    __syncthreads();
  }
  // full l reduction across the 16 column lanes
#pragma unroll
  for (int fm = 0; fm < 2; fm++)
#pragma unroll
    for (int st = 1; st < 16; st <<= 1)
#pragma unroll
      for (int r = 0; r < 4; r++)
        lrun[fm][r] += __shfl_xor(lrun[fm][r], st);
  // write ctx [B, S, H*DH] bf16
#pragma unroll
  for (int fm = 0; fm < 2; fm++)
#pragma unroll
    for (int fn = 0; fn < 4; fn++)
#pragma unroll
      for (int r = 0; r < 4; r++) {
        int srow = qb0 + fm * 16 + g * 4 + r;
        float v = Oacc[fm][fn][r] / lrun[fm][r];
        ctx[((size_t)b * 2048 + srow) * 1024 + h * 64 + fn * 16 + c] = __float2bfloat16(v);
      }
}

// ---------------- launch ----------------

extern "C" void kernel_launch(void* const* d_in, const int* in_sizes, int n_in,
                              void* d_out, int out_size, void* d_ws, size_t ws_size,
                              hipStream_t stream) {
  const float* x  = (const float*)d_in[0];
  const float* y  = (const float*)d_in[1];
  const float* Wq = (const float*)d_in[2];
  const float* Wk = (const float*)d_in[3];
  const float* Wv = (const float*)d_in[4];
  const float* Wo = (const float*)d_in[5];
  const float* bo = (const float*)d_in[6];
  const int* amask = (const int*)d_in[7];
  float* out = (float*)d_out;

  char* ws = (char*)d_ws;
  bf16* xb = (bf16*)ws;                              // 16 MB  (later reused as ctx)
  bf16* yb = (bf16*)(ws + 16777216);                 // 16 MB
  bf16* WT = (bf16*)(ws + 33554432);                 // 4 x 2 MB, order q,k,v,o
  bf16* Qb = (bf16*)(ws + 41943040);                 // 16 MB  [B,H,S,64]
  bf16* Kb = (bf16*)(ws + 58720256);                 // 16 MB  [B,H,S,64]
  bf16* Vt = (bf16*)(ws + 75497472);                 // 16 MB  [B,H,64,S]
  unsigned long long* mbits = (unsigned long long*)(ws + 92274688);  // 2 MB
  bf16* ctx = xb;  // alias: xb dead after K projection

  conv_bf16<<<8192, 256, 0, stream>>>(x, xb, 2097152);
  conv_bf16<<<8192, 256, 0, stream>>>(y, yb, 2097152);
  transpose_w<<<dim3(32, 32, 4), dim3(32, 8), 0, stream>>>(Wq, Wk, Wv, Wo, WT);
  maskpack<<<65536, 256, 0, stream>>>(amask, mbits);

  dim3 gg(64, 8);
  gemm_bt<0><<<gg, 256, 0, stream>>>(xb, WT + 0 * 1048576, Qb, nullptr);
  gemm_bt<0><<<gg, 256, 0, stream>>>(xb, WT + 1 * 1048576, Kb, nullptr);
  gemm_bt<1><<<gg, 256, 0, stream>>>(yb, WT + 2 * 1048576, Vt, nullptr);

  attn_kernel<<<dim3(16, 64), 256, 0, stream>>>(Qb, Kb, Vt, mbits, ctx);

  gemm_bt<2><<<gg, 256, 0, stream>>>(ctx, WT + 3 * 1048576, out, bo);
}

// Round 2
// 316.894 us; speedup vs baseline: 1.2441x; 1.2441x over previous
//
#include <hip/hip_runtime.h>
#include <hip/hip_bf16.h>
#include <stdint.h>

typedef __attribute__((ext_vector_type(8))) short short8;
typedef __attribute__((ext_vector_type(4))) float f32x4;
typedef __hip_bfloat16 bf16;

typedef __attribute__((address_space(3))) uint32_t lds_u32_t;
typedef __attribute__((address_space(1))) const uint32_t glb_u32_t;

__device__ __forceinline__ void gload_lds16(const void* g, void* l) {
  // stages 64 lanes x 16B: LDS dest = l + lane*16 (wave-uniform base), global src per-lane
  __builtin_amdgcn_global_load_lds((glb_u32_t*)g, (lds_u32_t*)l, 16, 0, 0);
}

// ---------------- prep kernels ----------------

__global__ void conv_bf16(const float* __restrict__ in, bf16* __restrict__ outp, int n4) {
  int i = blockIdx.x * blockDim.x + threadIdx.x;
  if (i >= n4) return;
  const float4 v = ((const float4*)in)[i];
  union { ushort4 u; bf16 h[4]; } o;
  o.h[0] = __float2bfloat16(v.x); o.h[1] = __float2bfloat16(v.y);
  o.h[2] = __float2bfloat16(v.z); o.h[3] = __float2bfloat16(v.w);
  ((ushort4*)outp)[i] = o.u;
}

// W [1024][1024] f32 row-major -> WT [n][k] bf16  (4 matrices via blockIdx.z)
__global__ void transpose_w(const float* __restrict__ W0, const float* __restrict__ W1,
                            const float* __restrict__ W2, const float* __restrict__ W3,
                            bf16* __restrict__ outp) {
  const float* W = blockIdx.z == 0 ? W0 : blockIdx.z == 1 ? W1 : blockIdx.z == 2 ? W2 : W3;
  bf16* o = outp + (size_t)blockIdx.z * 1048576;
  __shared__ float t[32][33];
  int x = threadIdx.x, y0 = threadIdx.y;            // (32,8)
  int c0 = blockIdx.x * 32, r0 = blockIdx.y * 32;
#pragma unroll
  for (int i = 0; i < 4; i++)
    t[y0 + i*8][x] = W[(size_t)(r0 + y0 + i*8)*1024 + c0 + x];
  __syncthreads();
#pragma unroll
  for (int i = 0; i < 4; i++)
    o[(size_t)(c0 + y0 + i*8)*1024 + r0 + x] = __float2bfloat16(t[x][y0 + i*8]);
}

// attention_mask [B,1,S,S] int32 -> bit-packed words: bit=1 means masked (mask==0)
__global__ void maskpack(const int* __restrict__ mask, unsigned long long* __restrict__ mbits) {
  int tid = threadIdx.x;
  int lane = tid & 63, wid = tid >> 6;
  size_t word = (size_t)blockIdx.x * 4 + wid;       // 262144 words total
  int v = mask[word * 64 + lane];
  unsigned long long bits = __ballot(v == 0);
  if (lane == 0) mbits[word] = bits;
}

// ---------------- GEMM (B-transposed): C[M=8192][N=1024] = A[M][1024] * Bt[N][1024]^T ----------------
// MODE 0: write bf16 to [B,H,S,64]  (Q,K)
// MODE 1: write bf16 to [B,H,64,S]  (V pre-transposed)
// MODE 2: write f32 row-major + bias (final output)
template<int MODE>
__global__ void gemm_bt(const bf16* __restrict__ A, const bf16* __restrict__ Bt,
                        void* __restrict__ Out, const float* __restrict__ bias) {
  const int tid = threadIdx.x;
  const int lane = tid & 63, wid = tid >> 6;
  const int g = lane >> 4, c = lane & 15;
  const int m0 = blockIdx.x * 128, n0 = blockIdx.y * 128;
  const int wm = wid >> 1, wn = wid & 1;
  __shared__ bf16 As[128 * 64];
  __shared__ bf16 Bs[128 * 64];
  f32x4 acc[4][4] = {};
  for (int k0 = 0; k0 < 1024; k0 += 64) {
#pragma unroll
    for (int i = 0; i < 4; i++) {
      int chunk = wid * 4 + i;          // 16 chunks of 1KB per matrix
      int idx = chunk * 64 + lane;      // 16B unit index
      int row = idx >> 3, u = idx & 7;  // 128B rows, 8 units each
      int koff = k0 + ((u ^ (row & 7)) * 8);   // pre-swizzled source (rule #21)
      gload_lds16(A  + (size_t)(m0 + row) * 1024 + koff, As + chunk * 512);
      gload_lds16(Bt + (size_t)(n0 + row) * 1024 + koff, Bs + chunk * 512);
    }
    __syncthreads();
#pragma unroll
    for (int kk = 0; kk < 2; kk++) {
      short8 af[4], bf_[4];
#pragma unroll
      for (int f = 0; f < 4; f++) {
        int ra = wm * 64 + f * 16 + c;
        af[f]  = *(const short8*)(As + ra * 64 + (((kk * 4 + g) ^ (ra & 7)) * 8));
        int rb = wn * 64 + f * 16 + c;
        bf_[f] = *(const short8*)(Bs + rb * 64 + (((kk * 4 + g) ^ (rb & 7)) * 8));
      }
#pragma unroll
      for (int fm = 0; fm < 4; fm++)
#pragma unroll
        for (int fn = 0; fn < 4; fn++)
          acc[fm][fn] = __builtin_amdgcn_mfma_f32_16x16x32_bf16(af[fm], bf_[fn], acc[fm][fn], 0, 0, 0);
    }
    __syncthreads();
  }
  // epilogue: C layout col = lane&15, row = (lane>>4)*4 + reg
#pragma unroll
  for (int fm = 0; fm < 4; fm++) {
#pragma unroll
    for (int fn = 0; fn < 4; fn++) {
      int gn = n0 + wn * 64 + fn * 16 + c;
#pragma unroll
      for (int r = 0; r < 4; r++) {
        int gm = m0 + wm * 64 + fm * 16 + g * 4 + r;
        float v = acc[fm][fn][r];
        if constexpr (MODE == 2) {
          ((float*)Out)[(size_t)gm * 1024 + gn] = v + bias[gn];
        } else if constexpr (MODE == 0) {
          int b = gm >> 11, s = gm & 2047, hh = gn >> 6, d = gn & 63;
          ((bf16*)Out)[(((size_t)b * 16 + hh) * 2048 + s) * 64 + d] = __float2bfloat16(v);
        } else {
          int b = gm >> 11, s = gm & 2047, hh = gn >> 6, d = gn & 63;
          ((bf16*)Out)[(((size_t)b * 16 + hh) * 64 + d) * 2048 + s] = __float2bfloat16(v);
        }
      }
    }
  }
}

// ---------------- flash attention ----------------
// grid (S/128=16, B*H=64), 256 threads. Wave w owns 32 q rows. KT=64.
// 2-phase double-buffered K/V staging (T3 minimum recipe): stage(t+1) issued
// before compute(t); single end-of-tile __syncthreads (implicit vmcnt(0)) drains
// loads that had a full compute phase to land. Defer-max (T13, THR=8 log2-units).
__global__ __launch_bounds__(256, 2) void attn_kernel(
    const bf16* __restrict__ Qb, const bf16* __restrict__ Kb, const bf16* __restrict__ Vt,
    const unsigned long long* __restrict__ mbits, bf16* __restrict__ ctx) {
  const int tid = threadIdx.x;
  const int lane = tid & 63, wid = tid >> 6;
  const int g = lane >> 4, c = lane & 15;
  const int bh = blockIdx.y;
  const int b = bh >> 4, h = bh & 15;
  const int qb0 = blockIdx.x * 128 + wid * 32;
  __shared__ bf16 Ks[2][64 * 64];
  __shared__ bf16 Vs[2][64 * 64];       // V^T tile: [dh][key]
  __shared__ bf16 Ps[4][32 * 72];       // per-wave P tile, padded stride 72
  const bf16* Qp = Qb + (size_t)bh * 2048 * 64;
  const bf16* Kp = Kb + (size_t)bh * 2048 * 64;
  const bf16* Vp = Vt + (size_t)bh * 64 * 2048;

  auto stage = [&](int kt, int sel) {
#pragma unroll
    for (int i = 0; i < 2; i++) {
      int chunk = wid * 2 + i;
      int idx = chunk * 64 + lane;
      int row = idx >> 3, u = idx & 7;
      gload_lds16(Kp + (size_t)(kt * 64 + row) * 64 + ((u ^ (row & 7)) * 8), &Ks[sel][chunk * 512]);
      gload_lds16(Vp + (size_t)row * 2048 + kt * 64 + ((u ^ (row & 7)) * 8), &Vs[sel][chunk * 512]);
    }
  };

  short8 qf[2][2];
#pragma unroll
  for (int fm = 0; fm < 2; fm++)
#pragma unroll
    for (int kk = 0; kk < 2; kk++)
      qf[fm][kk] = *(const short8*)(Qp + (size_t)(qb0 + fm * 16 + c) * 64 + kk * 32 + g * 8);

  f32x4 Oacc[2][4] = {};
  float mrun[2][4], lrun[2][4], mc1[2][4];
#pragma unroll
  for (int fm = 0; fm < 2; fm++)
#pragma unroll
    for (int r = 0; r < 4; r++) { mrun[fm][r] = -3.0e38f; lrun[fm][r] = 0.f; mc1[fm][r] = 0.f; }

  const float C1 = 0.18033688011112042f;   // (1/8)*log2(e): logits in log2 units
  const float NEGRAW = -1.0e9f;            // mask value BEFORE scale, as reference
  const float THRRAW = 44.36f;             // 8 log2-units in raw-score units

  unsigned long long mwC[2][4], mwN[2][4];
  stage(0, 0);
#pragma unroll
  for (int fm = 0; fm < 2; fm++)
#pragma unroll
    for (int r = 0; r < 4; r++)
      mwC[fm][r] = mbits[((size_t)b * 2048 + qb0 + fm * 16 + g * 4 + r) * 32 + 0];
  __syncthreads();   // drains tile-0 staging (only exposed latency in the kernel)

#pragma unroll 2
  for (int kt = 0; kt < 32; kt++) {
    const int sel = kt & 1;
    if (kt < 31) stage(kt + 1, sel ^ 1);
    {
      const int ktn = (kt + 1) & 31;
#pragma unroll
      for (int fm = 0; fm < 2; fm++)
#pragma unroll
        for (int r = 0; r < 4; r++)
          mwN[fm][r] = mbits[((size_t)b * 2048 + qb0 + fm * 16 + g * 4 + r) * 32 + ktn];
    }
    // ---- QK^T : raw scores[q][key] ----
    f32x4 sacc[2][4] = {};
#pragma unroll
    for (int kk = 0; kk < 2; kk++) {
      short8 bK[4];
#pragma unroll
      for (int fn = 0; fn < 4; fn++) {
        int row = fn * 16 + c;
        bK[fn] = *(const short8*)(&Ks[sel][row * 64 + (((kk * 4 + g) ^ (row & 7)) * 8)]);
      }
#pragma unroll
      for (int fm = 0; fm < 2; fm++)
#pragma unroll
        for (int fn = 0; fn < 4; fn++)
          sacc[fm][fn] = __builtin_amdgcn_mfma_f32_16x16x32_bf16(qf[fm][kk], bK[fn], sacc[fm][fn], 0, 0, 0);
    }
    // ---- mask (raw -1e9, pre-shifted bit words) + lane-local max ----
    float lmx = -3.0e38f;
#pragma unroll
    for (int fm = 0; fm < 2; fm++)
#pragma unroll
      for (int r = 0; r < 4; r++) {
        unsigned long long t = mwC[fm][r] >> c;
#pragma unroll
        for (int fn = 0; fn < 4; fn++) {
          float v = ((t >> (fn * 16)) & 1ull) ? NEGRAW : sacc[fm][fn][r];
          sacc[fm][fn][r] = v;
          lmx = fmaxf(lmx, v);
        }
      }
    // ---- defer-max check (conservative, cheap common path) ----
    float minm = fminf(fminf(fminf(mrun[0][0], mrun[0][1]), fminf(mrun[0][2], mrun[0][3])),
                       fminf(fminf(mrun[1][0], mrun[1][1]), fminf(mrun[1][2], mrun[1][3])));
    if (__any(lmx > minm + THRRAW)) {
#pragma unroll
      for (int fm = 0; fm < 2; fm++) {
        float mx[4];
#pragma unroll
        for (int r = 0; r < 4; r++)
          mx[r] = fmaxf(fmaxf(sacc[fm][0][r], sacc[fm][1][r]), fmaxf(sacc[fm][2][r], sacc[fm][3][r]));
#pragma unroll
        for (int st = 1; st < 16; st <<= 1)
#pragma unroll
          for (int r = 0; r < 4; r++)
            mx[r] = fmaxf(mx[r], __shfl_xor(mx[r], st));
#pragma unroll
        for (int r = 0; r < 4; r++) {
          float mnew = fmaxf(mrun[fm][r], mx[r]);
          float sc = exp2f((mrun[fm][r] - mnew) * C1);
          mrun[fm][r] = mnew; mc1[fm][r] = mnew * C1;
          lrun[fm][r] *= sc;
#pragma unroll
          for (int fn = 0; fn < 4; fn++) Oacc[fm][fn][r] *= sc;
        }
      }
    }
    // ---- P = exp2(fma(s, C1, -m*C1)) ----
#pragma unroll
    for (int fm = 0; fm < 2; fm++)
#pragma unroll
      for (int fn = 0; fn < 4; fn++)
#pragma unroll
        for (int r = 0; r < 4; r++) {
          float p = exp2f(fmaf(sacc[fm][fn][r], C1, -mc1[fm][r]));
          lrun[fm][r] += p;   // partial (this lane's columns); full reduce at end
          Ps[wid][(fm * 16 + g * 4 + r) * 72 + fn * 16 + c] = __float2bfloat16(p);
        }
    asm volatile("s_waitcnt lgkmcnt(0)" ::: "memory");  // P writes visible before reads
    __builtin_amdgcn_sched_barrier(0);
    // ---- PV: O[q][dh] += P[q][key] * V[key][dh] ----
#pragma unroll
    for (int kk = 0; kk < 2; kk++) {
      short8 pa[2], bV[4];
#pragma unroll
      for (int fm = 0; fm < 2; fm++)
        pa[fm] = *(const short8*)(&Ps[wid][(fm * 16 + c) * 72 + kk * 32 + g * 8]);
#pragma unroll
      for (int fn = 0; fn < 4; fn++) {
        int row = fn * 16 + c;
        bV[fn] = *(const short8*)(&Vs[sel][row * 64 + (((kk * 4 + g) ^ (row & 7)) * 8)]);
      }
#pragma unroll
      for (int fm = 0; fm < 2; fm++)
#pragma unroll
        for (int fn = 0; fn < 4; fn++)
          Oacc[fm][fn] = __builtin_amdgcn_mfma_f32_16x16x32_bf16(pa[fm], bV[fn], Oacc[fm][fn], 0, 0, 0);
    }
#pragma unroll
    for (int fm = 0; fm < 2; fm++)
#pragma unroll
      for (int r = 0; r < 4; r++) mwC[fm][r] = mwN[fm][r];
    __syncthreads();   // implicit vmcnt(0): drains tile kt+1 staging (hidden under this tile)
  }
  // full l reduction across the 16 column lanes
#pragma unroll
  for (int fm = 0; fm < 2; fm++)
#pragma unroll
    for (int st = 1; st < 16; st <<= 1)
#pragma unroll
      for (int r = 0; r < 4; r++)
        lrun[fm][r] += __shfl_xor(lrun[fm][r], st);
  // write ctx [B, S, H*DH] bf16
#pragma unroll
  for (int fm = 0; fm < 2; fm++)
#pragma unroll
    for (int fn = 0; fn < 4; fn++)
#pragma unroll
      for (int r = 0; r < 4; r++) {
        int srow = qb0 + fm * 16 + g * 4 + r;
        float v = Oacc[fm][fn][r] / lrun[fm][r];
        ctx[((size_t)b * 2048 + srow) * 1024 + h * 64 + fn * 16 + c] = __float2bfloat16(v);
      }
}

// ---------------- launch ----------------

extern "C" void kernel_launch(void* const* d_in, const int* in_sizes, int n_in,
                              void* d_out, int out_size, void* d_ws, size_t ws_size,
                              hipStream_t stream) {
  const float* x  = (const float*)d_in[0];
  const float* y  = (const float*)d_in[1];
  const float* Wq = (const float*)d_in[2];
  const float* Wk = (const float*)d_in[3];
  const float* Wv = (const float*)d_in[4];
  const float* Wo = (const float*)d_in[5];
  const float* bo = (const float*)d_in[6];
  const int* amask = (const int*)d_in[7];
  float* out = (float*)d_out;

  char* ws = (char*)d_ws;
  bf16* xb = (bf16*)ws;                              // 16 MB  (later reused as ctx)
  bf16* yb = (bf16*)(ws + 16777216);                 // 16 MB
  bf16* WT = (bf16*)(ws + 33554432);                 // 4 x 2 MB, order q,k,v,o
  bf16* Qb = (bf16*)(ws + 41943040);                 // 16 MB  [B,H,S,64]
  bf16* Kb = (bf16*)(ws + 58720256);                 // 16 MB  [B,H,S,64]
  bf16* Vt = (bf16*)(ws + 75497472);                 // 16 MB  [B,H,64,S]
  unsigned long long* mbits = (unsigned long long*)(ws + 92274688);  // 2 MB
  bf16* ctx = xb;  // alias: xb dead after K projection

  conv_bf16<<<8192, 256, 0, stream>>>(x, xb, 2097152);
  conv_bf16<<<8192, 256, 0, stream>>>(y, yb, 2097152);
  transpose_w<<<dim3(32, 32, 4), dim3(32, 8), 0, stream>>>(Wq, Wk, Wv, Wo, WT);
  maskpack<<<65536, 256, 0, stream>>>(amask, mbits);

  dim3 gg(64, 8);
  gemm_bt<0><<<gg, 256, 0, stream>>>(xb, WT + 0 * 1048576, Qb, nullptr);
  gemm_bt<0><<<gg, 256, 0, stream>>>(xb, WT + 1 * 1048576, Kb, nullptr);
  gemm_bt<1><<<gg, 256, 0, stream>>>(yb, WT + 2 * 1048576, Vt, nullptr);

  attn_kernel<<<dim3(16, 64), 256, 0, stream>>>(Qb, Kb, Vt, mbits, ctx);

  gemm_bt<2><<<gg, 256, 0, stream>>>(ctx, WT + 3 * 1048576, out, bo);
}